// Round 1
// baseline (324.340 us; speedup 1.0000x reference)
//
#include <hip/hip_runtime.h>
#include <math.h>

#define TOK 12544   // B*H*W
#define CDIM 128
#define HID 512
#define NHEAD 4
#define HD 32
#define KS 7
#define HSZ 56
#define WSZ 56

// ---------------- LayerNorm: one wave (64 lanes) per 128-elem row ----------------
__global__ void ln_kernel(const float* __restrict__ x, const float* __restrict__ w,
                          const float* __restrict__ b, float* __restrict__ y) {
    int row  = blockIdx.x * 4 + (threadIdx.x >> 6);
    int lane = threadIdx.x & 63;
    const float* xr = x + (size_t)row * CDIM;
    float v0 = xr[lane], v1 = xr[lane + 64];
    float s = v0 + v1;
    #pragma unroll
    for (int o = 32; o > 0; o >>= 1) s += __shfl_xor(s, o);
    float mu = s * (1.0f / 128.0f);
    float d0 = v0 - mu, d1 = v1 - mu;
    float sq = d0 * d0 + d1 * d1;
    #pragma unroll
    for (int o = 32; o > 0; o >>= 1) sq += __shfl_xor(sq, o);
    float rstd = rsqrtf(sq * (1.0f / 128.0f) + 1e-5f);
    float* yr = y + (size_t)row * CDIM;
    yr[lane]      = d0 * rstd * w[lane]      + b[lane];
    yr[lane + 64] = d1 * rstd * w[lane + 64] + b[lane + 64];
}

// ---------------- Row-block GEMM: Y[M x N] = X[M x KD] @ W^T + bias, epilogues ----------------
// 8 rows per block, N threads (one output column per thread per row).
// EPI: 0 = qkv (scale first CDIM outputs by 1/sqrt(32)), 1 = +residual, 2 = exact GELU
template<int N, int KD, int EPI>
__global__ void gemm_rows(const float* __restrict__ X, const float* __restrict__ W,
                          const float* __restrict__ bias, const float* __restrict__ res,
                          float* __restrict__ Y) {
    __shared__ float xs[8 * KD];
    int r0 = blockIdx.x * 8;
    const float* xblk = X + (size_t)r0 * KD;
    for (int idx = threadIdx.x; idx < 8 * KD / 4; idx += N)
        ((float4*)xs)[idx] = ((const float4*)xblk)[idx];
    __syncthreads();

    int n = threadIdx.x;
    float acc[8];
    #pragma unroll
    for (int r = 0; r < 8; r++) acc[r] = 0.f;
    const float* wr = W + (size_t)n * KD;
    #pragma unroll 4
    for (int k = 0; k < KD; k += 4) {
        float4 w4 = *(const float4*)(wr + k);
        #pragma unroll
        for (int r = 0; r < 8; r++) {
            const float* xr = xs + r * KD + k;
            acc[r] += xr[0] * w4.x + xr[1] * w4.y + xr[2] * w4.z + xr[3] * w4.w;
        }
    }
    float bn = bias[n];
    #pragma unroll
    for (int r = 0; r < 8; r++) {
        float v = acc[r] + bn;
        size_t o = (size_t)(r0 + r) * N + n;
        if (EPI == 0) {
            if (n < CDIM) v *= 0.17677669529663687f;  // 32^-0.5, pre-scale q
            Y[o] = v;
        } else if (EPI == 1) {
            Y[o] = v + res[o];
        } else {
            Y[o] = 0.5f * v * (1.0f + erff(v * 0.70710678118654752f));  // exact gelu
        }
    }
}

// ---------------- Neighborhood attention: one wave per (pixel, head) ----------------
// qkv layout per token: [3][NH][HD] floats (q pre-scaled).
__global__ void nat_attn(const float* __restrict__ qkv, const float* __restrict__ rpb,
                         float* __restrict__ out) {
    int wid  = blockIdx.x * 4 + (threadIdx.x >> 6);
    int lane = threadIdx.x & 63;
    int head = wid & (NHEAD - 1);
    int p    = wid >> 2;
    int j  = p % WSZ;
    int i  = (p / WSZ) % HSZ;
    int bb = p / (WSZ * HSZ);
    int sh = min(max(i - 3, 0), HSZ - KS);
    int sw = min(max(j - 3, 0), WSZ - KS);

    float score = -INFINITY;
    int nidx = 0;
    if (lane < KS * KS) {
        int ki = lane / KS, kj = lane % KS;
        int ih = sh + ki, jw = sw + kj;
        nidx = (bb * HSZ + ih) * WSZ + jw;
        const float* qp = qkv + (size_t)p * 384 + head * HD;
        const float* kp = qkv + (size_t)nidx * 384 + 128 + head * HD;
        float s = 0.f;
        #pragma unroll
        for (int d = 0; d < HD; d += 4) {
            float4 q4 = *(const float4*)(qp + d);
            float4 k4 = *(const float4*)(kp + d);
            s += q4.x * k4.x + q4.y * k4.y + q4.z * k4.z + q4.w * k4.w;
        }
        int bh = ih - i + 6, bw = jw - j + 6;
        score = s + rpb[head * 169 + bh * 13 + bw];
    }
    // 64-lane softmax over 49 active scores
    float m = score;
    #pragma unroll
    for (int o = 32; o > 0; o >>= 1) m = fmaxf(m, __shfl_xor(m, o));
    float e = (lane < KS * KS) ? __expf(score - m) : 0.f;
    float sum = e;
    #pragma unroll
    for (int o = 32; o > 0; o >>= 1) sum += __shfl_xor(sum, o);
    float attn = e / sum;

    // PV: lane d (0..31) accumulates out[d]; attn/neighbor broadcast via shuffle
    float acc = 0.f;
    int d = lane & 31;
    for (int l = 0; l < KS * KS; l++) {
        float a  = __shfl(attn, l);
        int   ni = __shfl(nidx, l);
        acc += a * qkv[(size_t)ni * 384 + 256 + head * HD + d];
    }
    if (lane < 32) out[(size_t)p * CDIM + head * HD + d] = acc;
}

extern "C" void kernel_launch(void* const* d_in, const int* in_sizes, int n_in,
                              void* d_out, int out_size, void* d_ws, size_t ws_size,
                              hipStream_t stream) {
    const float* x      = (const float*)d_in[0];
    const float* n1w    = (const float*)d_in[1];
    const float* n1b    = (const float*)d_in[2];
    const float* qkv_w  = (const float*)d_in[3];
    const float* qkv_b  = (const float*)d_in[4];
    const float* rpb    = (const float*)d_in[5];
    const float* proj_w = (const float*)d_in[6];
    const float* proj_b = (const float*)d_in[7];
    const float* n2w    = (const float*)d_in[8];
    const float* n2b    = (const float*)d_in[9];
    const float* fc1_w  = (const float*)d_in[10];
    const float* fc1_b  = (const float*)d_in[11];
    const float* fc2_w  = (const float*)d_in[12];
    const float* fc2_b  = (const float*)d_in[13];
    float* out = (float*)d_out;

    float* ws   = (float*)d_ws;
    float* xn   = ws;                       // TOK*128
    float* qkvb = xn + (size_t)TOK * CDIM;  // TOK*384
    float* ao   = qkvb + (size_t)TOK * 384; // TOK*128
    float* x2   = ao + (size_t)TOK * CDIM;  // TOK*128
    float* zn   = x2 + (size_t)TOK * CDIM;  // TOK*128
    float* hb   = zn + (size_t)TOK * CDIM;  // TOK*512

    ln_kernel<<<TOK / 4, 256, 0, stream>>>(x, n1w, n1b, xn);
    gemm_rows<384, 128, 0><<<TOK / 8, 384, 0, stream>>>(xn, qkv_w, qkv_b, nullptr, qkvb);
    nat_attn<<<TOK * NHEAD / 4, 256, 0, stream>>>(qkvb, rpb, ao);
    gemm_rows<128, 128, 1><<<TOK / 8, 128, 0, stream>>>(ao, proj_w, proj_b, x, x2);
    ln_kernel<<<TOK / 4, 256, 0, stream>>>(x2, n2w, n2b, zn);
    gemm_rows<512, 128, 2><<<TOK / 8, 512, 0, stream>>>(zn, fc1_w, fc1_b, nullptr, hb);
    gemm_rows<128, 512, 1><<<TOK / 8, 128, 0, stream>>>(hb, fc2_w, fc2_b, x2, out);
}

// Round 2
// 181.348 us; speedup vs baseline: 1.7885x; 1.7885x over previous
//
#include <hip/hip_runtime.h>
#include <math.h>

#define TOK 12544   // B*H*W
#define CDIM 128
#define NHEAD 4
#define HD 32
#define KS 7
#define HSZ 56
#define WSZ 56

typedef __attribute__((ext_vector_type(8))) short short8;   // bf16x8 mfma frag
typedef __attribute__((ext_vector_type(4))) float f32x4;

__device__ inline ushort f2b(float f) {                      // fp32 -> bf16 RNE
    uint u = __float_as_uint(f);
    u += 0x7fffu + ((u >> 16) & 1u);
    return (ushort)(u >> 16);
}

// ---------- convert the 4 weight matrices to bf16 into one contiguous buffer ----------
// segments: qkv_w [0,49152) proj_w [49152,65536) fc1_w [65536,131072) fc2_w [131072,196608)
__global__ void convert_w(const float* __restrict__ a, const float* __restrict__ b,
                          const float* __restrict__ c, const float* __restrict__ d,
                          ushort* __restrict__ wb) {
    int e = (blockIdx.x * 256 + threadIdx.x) * 4;
    const float* src;
    if (e < 49152)       src = a + e;
    else if (e < 65536)  src = b + (e - 49152);
    else if (e < 131072) src = c + (e - 65536);
    else                 src = d + (e - 131072);
    float4 v = *(const float4*)src;
    uint2 pk;
    pk.x = (uint)f2b(v.x) | ((uint)f2b(v.y) << 16);
    pk.y = (uint)f2b(v.z) | ((uint)f2b(v.w) << 16);
    *(uint2*)(wb + e) = pk;
}

// ---------- LayerNorm -> bf16 (one wave per 128-elem row, 2 elems/lane) ----------
__global__ void ln_bf16(const float* __restrict__ x, const float* __restrict__ w,
                        const float* __restrict__ b, ushort* __restrict__ y) {
    int row  = blockIdx.x * 4 + (threadIdx.x >> 6);
    int lane = threadIdx.x & 63;
    float2 v = *(const float2*)(x + (size_t)row * CDIM + lane * 2);
    float s = v.x + v.y;
    #pragma unroll
    for (int o = 32; o > 0; o >>= 1) s += __shfl_xor(s, o);
    float mu = s * (1.0f / 128.0f);
    float d0 = v.x - mu, d1 = v.y - mu;
    float sq = d0 * d0 + d1 * d1;
    #pragma unroll
    for (int o = 32; o > 0; o >>= 1) sq += __shfl_xor(sq, o);
    float rstd = rsqrtf(sq * (1.0f / 128.0f) + 1e-5f);
    float2 wv = *(const float2*)(w + lane * 2);
    float2 bv = *(const float2*)(b + lane * 2);
    float o0 = d0 * rstd * wv.x + bv.x;
    float o1 = d1 * rstd * wv.y + bv.y;
    ((uint*)(y + (size_t)row * CDIM))[lane] = (uint)f2b(o0) | ((uint)f2b(o1) << 16);
}

// ---------- MFMA bf16 GEMM: Y[M x N] = Xbf @ Wbf^T + bias (+epilogue) ----------
// block = 256 thr = 4 waves; tile 128(M) x 64(N); wave w: rows [m0+w*32, +32)
// mfma_f32_16x16x32_bf16: A[m][k] m=lane&15, k=(lane>>4)*8+j ; B[k][n] n=lane&15;
// C/D: col=lane&15, row=(lane>>4)*4+reg  (m89-verified)
// EPI: 0 = qkv (scale cols<128), 1 = +bias+res -> fp32, 2 = gelu -> bf16
template<int N, int KD, int EPI>
__global__ void gemm_mfma(const ushort* __restrict__ X, const ushort* __restrict__ W,
                          const float* __restrict__ bias, const float* __restrict__ res,
                          float* __restrict__ Yf, ushort* __restrict__ Yb) {
    int wv = threadIdx.x >> 6, lane = threadIdx.x & 63;
    int lr = lane & 15, kg = lane >> 4;
    int m0 = blockIdx.x * 128 + wv * 32;
    int n0 = blockIdx.y * 64;
    f32x4 acc[2][4] = {};
    const ushort* xa = X + (size_t)(m0 + lr) * KD + kg * 8;
    const ushort* xb = xa + (size_t)16 * KD;
    const ushort* wp = W + (size_t)(n0 + lr) * KD + kg * 8;
    #pragma unroll 4
    for (int k0 = 0; k0 < KD; k0 += 32) {
        short8 a0 = *(const short8*)(xa + k0);
        short8 a1 = *(const short8*)(xb + k0);
        #pragma unroll
        for (int ni = 0; ni < 4; ni++) {
            short8 bf = *(const short8*)(wp + (size_t)ni * 16 * KD + k0);
            acc[0][ni] = __builtin_amdgcn_mfma_f32_16x16x32_bf16(a0, bf, acc[0][ni], 0, 0, 0);
            acc[1][ni] = __builtin_amdgcn_mfma_f32_16x16x32_bf16(a1, bf, acc[1][ni], 0, 0, 0);
        }
    }
    #pragma unroll
    for (int mi = 0; mi < 2; mi++)
    #pragma unroll
    for (int ni = 0; ni < 4; ni++) {
        int col = n0 + ni * 16 + lr;
        float bn = bias[col];
        #pragma unroll
        for (int r = 0; r < 4; r++) {
            int row = m0 + mi * 16 + kg * 4 + r;
            size_t o = (size_t)row * N + col;
            float v = acc[mi][ni][r] + bn;
            if (EPI == 0) {
                if (col < CDIM) v *= 0.17677669529663687f;   // q pre-scale 32^-0.5
                Yf[o] = v;
            } else if (EPI == 1) {
                Yf[o] = v + res[o];
            } else {
                Yb[o] = f2b(0.5f * v * (1.0f + erff(v * 0.70710678118654752f)));
            }
        }
    }
}

// ---------- Neighborhood attention v2: block per (batch, head, 8x8 tile) ----------
// Stage 14x14 K/V halo in LDS (rows padded to 36 floats for bank spread).
// Quad of threads per pixel: thread s computes scores l = s,s+4,..., softmax via
// 2x shfl_xor within quad; PV: thread s owns out dims [s*8, s*8+8).
__global__ void nat_attn2(const float* __restrict__ qkv, const float* __restrict__ rpb,
                          ushort* __restrict__ ao) {
    __shared__ float ks[196][36];
    __shared__ float vs[196][36];
    int tid  = threadIdx.x;
    int blk  = blockIdx.x;
    int tile = blk % 49;
    int hb   = blk / 49;
    int head = hb & 3;
    int b    = hb >> 2;
    int r0 = (tile / 7) * 8, c0 = (tile % 7) * 8;
    int hr0 = min(max(r0 - 3, 0), HSZ - 14);
    int hc0 = min(max(c0 - 3, 0), WSZ - 14);

    const float* kbase = qkv + (size_t)b * HSZ * WSZ * 384 + 128 + head * HD;
    for (int idx = tid; idx < 196 * 8; idx += 256) {
        int t = idx >> 3, f = idx & 7;
        int gtok = (hr0 + t / 14) * WSZ + hc0 + t % 14;
        const float* tp = kbase + (size_t)gtok * 384 + f * 4;
        *(float4*)&ks[t][f * 4] = *(const float4*)tp;
        *(float4*)&vs[t][f * 4] = *(const float4*)(tp + 128);
    }
    __syncthreads();

    int p = tid >> 2, s = tid & 3;
    int pi = p >> 3, pj = p & 7;
    int i = r0 + pi, j = c0 + pj;
    int shh = min(max(i - 3, 0), HSZ - KS);
    int sww = min(max(j - 3, 0), WSZ - KS);
    int di = shh - hr0, dj = sww - hc0;
    int gp = (b * HSZ + i) * WSZ + j;

    float q[32];
    const float* qp = qkv + (size_t)gp * 384 + head * HD;
    #pragma unroll
    for (int d = 0; d < 32; d += 4) {
        float4 t4 = *(const float4*)(qp + d);
        q[d] = t4.x; q[d + 1] = t4.y; q[d + 2] = t4.z; q[d + 3] = t4.w;
    }
    const float* bp = rpb + head * 169 + (shh - i + 6) * 13 + (sww - j + 6);

    float sc[13];
    float m = -INFINITY;
    #pragma unroll
    for (int it = 0; it < 13; it++) {
        int l = it * 4 + s;
        if (l < 49) {
            int ki = l / 7, kj = l % 7;
            int krow = (di + ki) * 14 + dj + kj;
            const float* kr = &ks[krow][0];
            float a = 0.f;
            #pragma unroll
            for (int d = 0; d < 32; d += 4) {
                float4 k4 = *(const float4*)(kr + d);
                a += q[d] * k4.x + q[d+1] * k4.y + q[d+2] * k4.z + q[d+3] * k4.w;
            }
            sc[it] = a + bp[ki * 13 + kj];
        } else sc[it] = -INFINITY;
        m = fmaxf(m, sc[it]);
    }
    m = fmaxf(m, __shfl_xor(m, 1));
    m = fmaxf(m, __shfl_xor(m, 2));
    float sum = 0.f;
    #pragma unroll
    for (int it = 0; it < 13; it++) {
        sc[it] = (it * 4 + s < 49) ? __expf(sc[it] - m) : 0.f;
        sum += sc[it];
    }
    sum += __shfl_xor(sum, 1);
    sum += __shfl_xor(sum, 2);
    float inv = 1.0f / sum;
    #pragma unroll
    for (int it = 0; it < 13; it++) sc[it] *= inv;

    float oa[8] = {};
    int qbase = (tid & 63) & ~3;
    #pragma unroll
    for (int l = 0; l < 49; l++) {
        float a = __shfl(sc[l >> 2], qbase + (l & 3));
        int krow = (di + l / 7) * 14 + dj + l % 7;
        const float* vr = &vs[krow][s * 8];
        #pragma unroll
        for (int d2 = 0; d2 < 8; d2++) oa[d2] += a * vr[d2];
    }
    uint4 pk;
    pk.x = (uint)f2b(oa[0]) | ((uint)f2b(oa[1]) << 16);
    pk.y = (uint)f2b(oa[2]) | ((uint)f2b(oa[3]) << 16);
    pk.z = (uint)f2b(oa[4]) | ((uint)f2b(oa[5]) << 16);
    pk.w = (uint)f2b(oa[6]) | ((uint)f2b(oa[7]) << 16);
    *(uint4*)(ao + (size_t)gp * CDIM + head * HD + s * 8) = pk;
}

extern "C" void kernel_launch(void* const* d_in, const int* in_sizes, int n_in,
                              void* d_out, int out_size, void* d_ws, size_t ws_size,
                              hipStream_t stream) {
    const float* x      = (const float*)d_in[0];
    const float* n1w    = (const float*)d_in[1];
    const float* n1b    = (const float*)d_in[2];
    const float* qkv_w  = (const float*)d_in[3];
    const float* qkv_b  = (const float*)d_in[4];
    const float* rpb    = (const float*)d_in[5];
    const float* proj_w = (const float*)d_in[6];
    const float* proj_b = (const float*)d_in[7];
    const float* n2w    = (const float*)d_in[8];
    const float* n2b    = (const float*)d_in[9];
    const float* fc1_w  = (const float*)d_in[10];
    const float* fc1_b  = (const float*)d_in[11];
    const float* fc2_w  = (const float*)d_in[12];
    const float* fc2_b  = (const float*)d_in[13];
    float* out = (float*)d_out;

    ushort* wb   = (ushort*)d_ws;                        // 196608 bf16 weights
    ushort* xnb  = wb + 196608;                          // TOK*128 bf16
    float*  qkvb = (float*)(xnb + (size_t)TOK * CDIM);   // TOK*384 f32
    ushort* aob  = (ushort*)(qkvb + (size_t)TOK * 384);  // TOK*128 bf16
    float*  x2   = (float*)(aob + (size_t)TOK * CDIM);   // TOK*128 f32
    ushort* znb  = (ushort*)(x2 + (size_t)TOK * CDIM);   // TOK*128 bf16
    ushort* hbb  = znb + (size_t)TOK * CDIM;             // TOK*512 bf16

    const ushort* w_qkv  = wb;
    const ushort* w_proj = wb + 49152;
    const ushort* w_fc1  = wb + 65536;
    const ushort* w_fc2  = wb + 131072;

    convert_w<<<192, 256, 0, stream>>>(qkv_w, proj_w, fc1_w, fc2_w, wb);
    ln_bf16<<<TOK / 4, 256, 0, stream>>>(x, n1w, n1b, xnb);
    gemm_mfma<384, 128, 0><<<dim3(98, 6), 256, 0, stream>>>(xnb, w_qkv, qkv_b, nullptr, qkvb, nullptr);
    nat_attn2<<<4 * NHEAD * 49, 256, 0, stream>>>(qkvb, rpb, aob);
    gemm_mfma<128, 128, 1><<<dim3(98, 2), 256, 0, stream>>>(aob, w_proj, proj_b, x, x2, nullptr);
    ln_bf16<<<TOK / 4, 256, 0, stream>>>(x2, n2w, n2b, znb);
    gemm_mfma<512, 128, 2><<<dim3(98, 8), 256, 0, stream>>>(znb, w_fc1, fc1_b, nullptr, nullptr, hbb);
    gemm_mfma<128, 512, 1><<<dim3(98, 2), 256, 0, stream>>>(hbb, w_fc2, fc2_b, x2, out, nullptr);
}

// Round 3
// 94.716 us; speedup vs baseline: 3.4244x; 1.9147x over previous
//
#include <hip/hip_runtime.h>
#include <math.h>

#define TOK 12544   // B*H*W
#define CDIM 128
#define NHEAD 4
#define HD 32
#define KS 7
#define HSZ 56
#define WSZ 56

typedef __attribute__((ext_vector_type(8))) short short8;   // bf16x8 mfma frag
typedef __attribute__((ext_vector_type(4))) float f32x4;

__device__ inline ushort f2b(float f) {                      // fp32 -> bf16 RNE
    uint u = __float_as_uint(f);
    u += 0x7fffu + ((u >> 16) & 1u);
    return (ushort)(u >> 16);
}

// ---------- convert the 4 weight matrices to bf16 into one contiguous buffer ----------
__global__ void convert_w(const float* __restrict__ a, const float* __restrict__ b,
                          const float* __restrict__ c, const float* __restrict__ d,
                          ushort* __restrict__ wb) {
    int e = (blockIdx.x * 256 + threadIdx.x) * 4;
    const float* src;
    if (e < 49152)       src = a + e;
    else if (e < 65536)  src = b + (e - 49152);
    else if (e < 131072) src = c + (e - 65536);
    else                 src = d + (e - 131072);
    float4 v = *(const float4*)src;
    uint2 pk;
    pk.x = (uint)f2b(v.x) | ((uint)f2b(v.y) << 16);
    pk.y = (uint)f2b(v.z) | ((uint)f2b(v.w) << 16);
    *(uint2*)(wb + e) = pk;
}

// ---------- LayerNorm -> bf16 (one wave per 128-elem row, 2 elems/lane) ----------
__global__ void ln_bf16(const float* __restrict__ x, const float* __restrict__ w,
                        const float* __restrict__ b, ushort* __restrict__ y) {
    int row  = blockIdx.x * 4 + (threadIdx.x >> 6);
    int lane = threadIdx.x & 63;
    float2 v = *(const float2*)(x + (size_t)row * CDIM + lane * 2);
    float s = v.x + v.y;
    #pragma unroll
    for (int o = 32; o > 0; o >>= 1) s += __shfl_xor(s, o);
    float mu = s * (1.0f / 128.0f);
    float d0 = v.x - mu, d1 = v.y - mu;
    float sq = d0 * d0 + d1 * d1;
    #pragma unroll
    for (int o = 32; o > 0; o >>= 1) sq += __shfl_xor(sq, o);
    float rstd = rsqrtf(sq * (1.0f / 128.0f) + 1e-5f);
    float2 wv = *(const float2*)(w + lane * 2);
    float2 bv = *(const float2*)(b + lane * 2);
    float o0 = d0 * rstd * wv.x + bv.x;
    float o1 = d1 * rstd * wv.y + bv.y;
    ((uint*)(y + (size_t)row * CDIM))[lane] = (uint)f2b(o0) | ((uint)f2b(o1) << 16);
}

// ---------- MFMA bf16 GEMM (unchanged from R1, validated) ----------
template<int N, int KD, int EPI>
__global__ void gemm_mfma(const ushort* __restrict__ X, const ushort* __restrict__ W,
                          const float* __restrict__ bias, const float* __restrict__ res,
                          float* __restrict__ Yf, ushort* __restrict__ Yb) {
    int wv = threadIdx.x >> 6, lane = threadIdx.x & 63;
    int lr = lane & 15, kg = lane >> 4;
    int m0 = blockIdx.x * 128 + wv * 32;
    int n0 = blockIdx.y * 64;
    f32x4 acc[2][4] = {};
    const ushort* xa = X + (size_t)(m0 + lr) * KD + kg * 8;
    const ushort* xb = xa + (size_t)16 * KD;
    const ushort* wp = W + (size_t)(n0 + lr) * KD + kg * 8;
    #pragma unroll 4
    for (int k0 = 0; k0 < KD; k0 += 32) {
        short8 a0 = *(const short8*)(xa + k0);
        short8 a1 = *(const short8*)(xb + k0);
        #pragma unroll
        for (int ni = 0; ni < 4; ni++) {
            short8 bf = *(const short8*)(wp + (size_t)ni * 16 * KD + k0);
            acc[0][ni] = __builtin_amdgcn_mfma_f32_16x16x32_bf16(a0, bf, acc[0][ni], 0, 0, 0);
            acc[1][ni] = __builtin_amdgcn_mfma_f32_16x16x32_bf16(a1, bf, acc[1][ni], 0, 0, 0);
        }
    }
    #pragma unroll
    for (int mi = 0; mi < 2; mi++)
    #pragma unroll
    for (int ni = 0; ni < 4; ni++) {
        int col = n0 + ni * 16 + lr;
        float bn = bias[col];
        #pragma unroll
        for (int r = 0; r < 4; r++) {
            int row = m0 + mi * 16 + kg * 4 + r;
            size_t o = (size_t)row * N + col;
            float v = acc[mi][ni][r] + bn;
            if (EPI == 0) {
                if (col < CDIM) v *= 0.17677669529663687f;   // q pre-scale 32^-0.5
                Yf[o] = v;
            } else if (EPI == 1) {
                Yf[o] = v + res[o];
            } else {
                Yb[o] = f2b(0.5f * v * (1.0f + erff(v * 0.70710678118654752f)));
            }
        }
    }
}

// ---------- Neighborhood attention v3: spill-free, scores live in LDS ----------
// Block per (batch, head, 8x8 tile). LDS: 14x14 K/V halo + att[64][53].
// Quad thread s: scores l = s,s+4,...; softmax via LDS re-read + 2x shfl_xor;
// PV reads attn from LDS (quad broadcast), V as float4; 1/sum folded into store.
__global__ void nat_attn3(const float* __restrict__ qkv, const float* __restrict__ rpb,
                          ushort* __restrict__ ao) {
    __shared__ float ks[196][36];
    __shared__ float vs[196][36];
    __shared__ float att[64][53];
    int tid  = threadIdx.x;
    int blk  = blockIdx.x;
    int tile = blk % 49;
    int hb   = blk / 49;
    int head = hb & 3;
    int b    = hb >> 2;
    int r0 = (tile / 7) * 8, c0 = (tile % 7) * 8;
    int hr0 = min(max(r0 - 3, 0), HSZ - 14);
    int hc0 = min(max(c0 - 3, 0), WSZ - 14);

    const float* kbase = qkv + (size_t)b * HSZ * WSZ * 384 + 128 + head * HD;
    for (int idx = tid; idx < 196 * 8; idx += 256) {
        int t = idx >> 3, f = idx & 7;
        int gtok = (hr0 + t / 14) * WSZ + hc0 + t % 14;
        const float* tp = kbase + (size_t)gtok * 384 + f * 4;
        *(float4*)&ks[t][f * 4] = *(const float4*)tp;
        *(float4*)&vs[t][f * 4] = *(const float4*)(tp + 128);
    }
    __syncthreads();

    int p = tid >> 2, s = tid & 3;
    int pi = p >> 3, pj = p & 7;
    int i = r0 + pi, j = c0 + pj;
    int shh = min(max(i - 3, 0), HSZ - KS);
    int sww = min(max(j - 3, 0), WSZ - KS);
    int di = shh - hr0, dj = sww - hc0;
    int gp = (b * HSZ + i) * WSZ + j;

    // q in registers: 8x float4, statically accessed only
    const float* qp = qkv + (size_t)gp * 384 + head * HD;
    float4 q0 = *(const float4*)(qp +  0), q1 = *(const float4*)(qp +  4);
    float4 q2 = *(const float4*)(qp +  8), q3 = *(const float4*)(qp + 12);
    float4 q4 = *(const float4*)(qp + 16), q5 = *(const float4*)(qp + 20);
    float4 q6 = *(const float4*)(qp + 24), q7 = *(const float4*)(qp + 28);
    const float* bp = rpb + head * 169 + (shh - i + 6) * 13 + (sww - j + 6);

    // phase 1: raw scores -> LDS
    for (int it = 0; it < 13; it++) {
        int l = it * 4 + s;
        if (l < 49) {
            int ki = l / 7, kj = l % 7;
            const float* kr = &ks[(di + ki) * 14 + dj + kj][0];
            float4 k4;
            float a = 0.f;
            k4 = *(const float4*)(kr +  0); a += q0.x*k4.x + q0.y*k4.y + q0.z*k4.z + q0.w*k4.w;
            k4 = *(const float4*)(kr +  4); a += q1.x*k4.x + q1.y*k4.y + q1.z*k4.z + q1.w*k4.w;
            k4 = *(const float4*)(kr +  8); a += q2.x*k4.x + q2.y*k4.y + q2.z*k4.z + q2.w*k4.w;
            k4 = *(const float4*)(kr + 12); a += q3.x*k4.x + q3.y*k4.y + q3.z*k4.z + q3.w*k4.w;
            k4 = *(const float4*)(kr + 16); a += q4.x*k4.x + q4.y*k4.y + q4.z*k4.z + q4.w*k4.w;
            k4 = *(const float4*)(kr + 20); a += q5.x*k4.x + q5.y*k4.y + q5.z*k4.z + q5.w*k4.w;
            k4 = *(const float4*)(kr + 24); a += q6.x*k4.x + q6.y*k4.y + q6.z*k4.z + q6.w*k4.w;
            k4 = *(const float4*)(kr + 28); a += q7.x*k4.x + q7.y*k4.y + q7.z*k4.z + q7.w*k4.w;
            att[p][l] = a + bp[ki * 13 + kj];
        }
    }

    // phase 2: softmax (own entries only; quad reduce via shfl)
    float m = -INFINITY;
    for (int it = 0; it < 13; it++) {
        int l = it * 4 + s;
        if (l < 49) m = fmaxf(m, att[p][l]);
    }
    m = fmaxf(m, __shfl_xor(m, 1));
    m = fmaxf(m, __shfl_xor(m, 2));
    float sum = 0.f;
    for (int it = 0; it < 13; it++) {
        int l = it * 4 + s;
        if (l < 49) {
            float e = __expf(att[p][l] - m);
            att[p][l] = e;
            sum += e;
        }
    }
    sum += __shfl_xor(sum, 1);
    sum += __shfl_xor(sum, 2);
    float inv = 1.0f / sum;
    __syncthreads();

    // phase 3: PV with unnormalized weights, static nested loops
    float oa[8] = {};
    #pragma unroll
    for (int ki = 0; ki < 7; ki++) {
        int rowb = (di + ki) * 14 + dj;
        #pragma unroll
        for (int kj = 0; kj < 7; kj++) {
            float a = att[p][ki * 7 + kj];
            const float* vr = &vs[rowb + kj][s * 8];
            float4 v0 = *(const float4*)vr;
            float4 v1 = *(const float4*)(vr + 4);
            oa[0] += a * v0.x; oa[1] += a * v0.y; oa[2] += a * v0.z; oa[3] += a * v0.w;
            oa[4] += a * v1.x; oa[5] += a * v1.y; oa[6] += a * v1.z; oa[7] += a * v1.w;
        }
    }
    uint4 pk;
    pk.x = (uint)f2b(oa[0] * inv) | ((uint)f2b(oa[1] * inv) << 16);
    pk.y = (uint)f2b(oa[2] * inv) | ((uint)f2b(oa[3] * inv) << 16);
    pk.z = (uint)f2b(oa[4] * inv) | ((uint)f2b(oa[5] * inv) << 16);
    pk.w = (uint)f2b(oa[6] * inv) | ((uint)f2b(oa[7] * inv) << 16);
    *(uint4*)(ao + (size_t)gp * CDIM + head * HD + s * 8) = pk;
}

extern "C" void kernel_launch(void* const* d_in, const int* in_sizes, int n_in,
                              void* d_out, int out_size, void* d_ws, size_t ws_size,
                              hipStream_t stream) {
    const float* x      = (const float*)d_in[0];
    const float* n1w    = (const float*)d_in[1];
    const float* n1b    = (const float*)d_in[2];
    const float* qkv_w  = (const float*)d_in[3];
    const float* qkv_b  = (const float*)d_in[4];
    const float* rpb    = (const float*)d_in[5];
    const float* proj_w = (const float*)d_in[6];
    const float* proj_b = (const float*)d_in[7];
    const float* n2w    = (const float*)d_in[8];
    const float* n2b    = (const float*)d_in[9];
    const float* fc1_w  = (const float*)d_in[10];
    const float* fc1_b  = (const float*)d_in[11];
    const float* fc2_w  = (const float*)d_in[12];
    const float* fc2_b  = (const float*)d_in[13];
    float* out = (float*)d_out;

    ushort* wb   = (ushort*)d_ws;                        // 196608 bf16 weights
    ushort* xnb  = wb + 196608;                          // TOK*128 bf16
    float*  qkvb = (float*)(xnb + (size_t)TOK * CDIM);   // TOK*384 f32
    ushort* aob  = (ushort*)(qkvb + (size_t)TOK * 384);  // TOK*128 bf16
    float*  x2   = (float*)(aob + (size_t)TOK * CDIM);   // TOK*128 f32
    ushort* znb  = (ushort*)(x2 + (size_t)TOK * CDIM);   // TOK*128 bf16
    ushort* hbb  = znb + (size_t)TOK * CDIM;             // TOK*512 bf16

    const ushort* w_qkv  = wb;
    const ushort* w_proj = wb + 49152;
    const ushort* w_fc1  = wb + 65536;
    const ushort* w_fc2  = wb + 131072;

    convert_w<<<192, 256, 0, stream>>>(qkv_w, proj_w, fc1_w, fc2_w, wb);
    ln_bf16<<<TOK / 4, 256, 0, stream>>>(x, n1w, n1b, xnb);
    gemm_mfma<384, 128, 0><<<dim3(98, 6), 256, 0, stream>>>(xnb, w_qkv, qkv_b, nullptr, qkvb, nullptr);
    nat_attn3<<<4 * NHEAD * 49, 256, 0, stream>>>(qkvb, rpb, aob);
    gemm_mfma<128, 128, 1><<<dim3(98, 2), 256, 0, stream>>>(aob, w_proj, proj_b, x, x2, nullptr);
    ln_bf16<<<TOK / 4, 256, 0, stream>>>(x2, n2w, n2b, znb);
    gemm_mfma<512, 128, 2><<<dim3(98, 8), 256, 0, stream>>>(znb, w_fc1, fc1_b, nullptr, nullptr, hbb);
    gemm_mfma<128, 512, 1><<<dim3(98, 2), 256, 0, stream>>>(hbb, w_fc2, fc2_b, x2, out, nullptr);
}